// Round 4
// baseline (1144.748 us; speedup 1.0000x reference)
//
#include <hip/hip_runtime.h>
#include <hip/hip_bf16.h>
#include <hip/hip_fp16.h>

typedef _Float16 f16;
typedef _Float16 f16x2 __attribute__((ext_vector_type(2)));
typedef _Float16 f16x8 __attribute__((ext_vector_type(8)));
typedef float f32x4 __attribute__((ext_vector_type(4)));

#define HEADS 8
#define HID 64
#define NCLS 40
#define FEAT 512

// ---------------- packing ----------------
// Wh_t[c][k] = W[c>>6][k][c&63], c in [0,512)   ([col][K] f16)
__global__ void pack_Wh(const float* __restrict__ W, f16* __restrict__ Wt) {
    int idx = blockIdx.x * blockDim.x + threadIdx.x;
    if (idx >= 512 * 512) return;
    int c = idx >> 9, k = idx & 511;
    Wt[idx] = (f16)W[(c >> 6) * 512 * 64 + k * 64 + (c & 63)];
}

// Bp_t[head][c][k] = W_pair[head][(c>>6)*64 + k][c&63], c in [0,128), k in [0,64)
__global__ void pack_Bp(const float* __restrict__ Wp, f16* __restrict__ Bt) {
    int idx = blockIdx.x * blockDim.x + threadIdx.x;
    if (idx >= 8 * 128 * 64) return;
    int head = idx >> 13, c = (idx >> 6) & 127, k = idx & 63;
    Bt[idx] = (f16)Wp[head * 8192 + ((c >> 6) * 64 + k) * 64 + (c & 63)];
}

// Wo_t[c][k] = W_out[k][c], c in [0,40)
__global__ void pack_Wo(const float* __restrict__ Wo, f16* __restrict__ Wt) {
    int idx = blockIdx.x * blockDim.x + threadIdx.x;
    if (idx >= 40 * 512) return;
    int c = idx >> 9, k = idx & 511;
    Wt[idx] = (f16)Wo[k * 40 + c];
}

// B2p[k][p*40+j] = W_pair_out[p*40+k][j]  (f32, for the tiny vector GEMM)
__global__ void repack_wpo(const float* __restrict__ Wpo, float* __restrict__ B2p) {
    int idx = blockIdx.x * blockDim.x + threadIdx.x;
    if (idx >= 40 * 80) return;
    int k = idx / 80;
    int c = idx % 80;
    int p = c / 40;
    int j = c % 40;
    B2p[idx] = Wpo[(p * 40 + k) * 40 + j];
}

// ---------------- CSR build (group edges by src == target row) ----------------
__global__ void hist_kernel(const int* __restrict__ src, int* __restrict__ counts, int ne) {
    int i = blockIdx.x * blockDim.x + threadIdx.x;
    int stride = gridDim.x * blockDim.x;
    for (; i < ne; i += stride) atomicAdd(&counts[src[i]], 1);
}

__global__ void scan_kernel(const int* __restrict__ counts, int* __restrict__ offsets,
                            int* __restrict__ cursor, int n) {
    __shared__ int part[1024];
    int tid = threadIdx.x;
    int chunk = (n + 1023) >> 10;
    int begin = tid * chunk;
    int end = begin + chunk;
    if (end > n) end = n;
    int s = 0;
    for (int i = begin; i < end; i++) s += counts[i];
    part[tid] = s;
    __syncthreads();
    for (int d = 1; d < 1024; d <<= 1) {
        int v = 0;
        if (tid >= d) v = part[tid - d];
        __syncthreads();
        if (tid >= d) part[tid] += v;
        __syncthreads();
    }
    int run = (tid == 0) ? 0 : part[tid - 1];
    for (int i = begin; i < end; i++) {
        cursor[i] = run;
        run += counts[i];
        offsets[i + 1] = run;
    }
    if (tid == 0) offsets[0] = 0;
}

__global__ void scatter_kernel(const int* __restrict__ src, const int* __restrict__ dst,
                               int* __restrict__ cursor, int* __restrict__ dsts, int ne) {
    int i = blockIdx.x * blockDim.x + threadIdx.x;
    int stride = gridDim.x * blockDim.x;
    for (; i < ne; i += stride) {
        int pos = atomicAdd(&cursor[src[i]], 1);
        dsts[pos] = dst[i];
    }
}

// ---------------- MFMA f16 GEMM: 128x128 tile, BK=32, 4 waves ----------------
__device__ __forceinline__ void stC(float* p, float v) { *p = v; }
__device__ __forceinline__ void stC(f16* p, float v) { *p = (f16)v; }
__device__ __forceinline__ f16x8 ldA8(const f16* p) { return *(const f16x8*)p; }
__device__ __forceinline__ f16x8 ldA8(const float* p) {
    float4 a = ((const float4*)p)[0];
    float4 b = ((const float4*)p)[1];
    f16x8 r = {(f16)a.x, (f16)a.y, (f16)a.z, (f16)a.w, (f16)b.x, (f16)b.y, (f16)b.z, (f16)b.w};
    return r;
}

// A [M][lda] (cols a0.. a0+K), Bt [batch][ncols][K] f16 (transposed), C [M][ldc]
template <typename AT, typename CT>
__global__ __launch_bounds__(256)
void gemm_mfma(const AT* __restrict__ A, int lda, int acol0, int acolStride,
               const f16* __restrict__ Bt, long bBatchStride, int K,
               CT* __restrict__ C, int ldc, int ccolStride,
               int nrows, int ncols) {
    __shared__ f16 As[128][40];   // BK=32 padded to 40 (80B rows -> 2-way max on b128 reads)
    __shared__ f16 Bs[128][40];
    const int batch = blockIdx.y;
    const int row0 = blockIdx.x * 128;
    const int col0 = blockIdx.z * 128;
    const int a0 = acol0 + batch * acolStride;
    const f16* Bb = Bt + (size_t)batch * bBatchStride;
    const int tid = threadIdx.x;
    const int lane = tid & 63;
    const int wave = tid >> 6;
    const int wr = (wave >> 1) * 64;
    const int wc = (wave & 1) * 64;
    f32x4 acc[4][4] = {};

    for (int k0 = 0; k0 < K; k0 += 32) {
#pragma unroll
        for (int i = 0; i < 2; i++) {
            int idx = tid + i * 256;
            int r = idx >> 2, ch = idx & 3;
            int gr = row0 + r;
            f16x8 val = {};
            if (gr < nrows) val = ldA8(A + (size_t)gr * lda + a0 + k0 + ch * 8);
            *(f16x8*)(&As[r][ch * 8]) = val;
        }
#pragma unroll
        for (int i = 0; i < 2; i++) {
            int idx = tid + i * 256;
            int r = idx >> 2, ch = idx & 3;
            int gc = col0 + r;
            f16x8 val = {};
            if (gc < ncols) val = *(const f16x8*)(Bb + (size_t)gc * K + k0 + ch * 8);
            *(f16x8*)(&Bs[r][ch * 8]) = val;
        }
        __syncthreads();
        f16x8 af[4], bf[4];
#pragma unroll
        for (int t = 0; t < 4; t++)
            af[t] = *(const f16x8*)(&As[wr + t * 16 + (lane & 15)][(lane >> 4) * 8]);
#pragma unroll
        for (int t = 0; t < 4; t++)
            bf[t] = *(const f16x8*)(&Bs[wc + t * 16 + (lane & 15)][(lane >> 4) * 8]);
#pragma unroll
        for (int i = 0; i < 4; i++)
#pragma unroll
            for (int j = 0; j < 4; j++)
                acc[i][j] = __builtin_amdgcn_mfma_f32_16x16x32_f16(af[i], bf[j], acc[i][j], 0, 0, 0);
        __syncthreads();
    }
    // C/D layout: col = lane&15, row = (lane>>4)*4 + r   [HW-verified]
    const int crow = (lane >> 4) * 4;
    const int ccol = lane & 15;
#pragma unroll
    for (int i = 0; i < 4; i++) {
#pragma unroll
        for (int j = 0; j < 4; j++) {
            int gc = col0 + wc + j * 16 + ccol;
            if (gc >= ncols) continue;
#pragma unroll
            for (int r = 0; r < 4; r++) {
                int gr = row0 + wr + i * 16 + crow + r;
                if (gr < nrows)
                    stC(&C[(size_t)gr * ldc + (size_t)batch * ccolStride + gc], acc[i][j][r]);
            }
        }
    }
}

// ---------------- tiny fp32 vector GEMM (kept for uv2: K=40, N=80) ----------------
__global__ void gemm_kernel(const float* __restrict__ A, int lda,
                            const float* __restrict__ B, int ldb,
                            float* __restrict__ C, int ldc,
                            int nrows, int K, int ncols) {
    __shared__ __align__(16) float As[16][68];
    __shared__ __align__(16) float Bs[16][64];
    const int colblk = blockIdx.z * 64;
    const int row0 = blockIdx.x * 64;
    const int tid = threadIdx.x;
    const int tm = tid >> 4, tn = tid & 15;
    float acc[4][4] = {};
    for (int k0 = 0; k0 < K; k0 += 16) {
#pragma unroll
        for (int i = 0; i < 4; i++) {
            int idx = tid + i * 256;
            int m = idx >> 4;
            int k = idx & 15;
            int gr = row0 + m;
            float v = 0.f;
            if (gr < nrows && (k0 + k) < K) v = A[(size_t)gr * lda + k0 + k];
            As[k][m] = v;
        }
#pragma unroll
        for (int i = 0; i < 4; i++) {
            int idx = tid + i * 256;
            int k = idx >> 6;
            int j = idx & 63;
            float v = 0.f;
            if ((k0 + k) < K && (colblk + j) < ncols) v = B[(size_t)(k0 + k) * ldb + colblk + j];
            Bs[k][j] = v;
        }
        __syncthreads();
#pragma unroll
        for (int k = 0; k < 16; k++) {
            float av[4], bv[4];
#pragma unroll
            for (int i = 0; i < 4; i++) av[i] = As[k][tm * 4 + i];
#pragma unroll
            for (int j = 0; j < 4; j++) bv[j] = Bs[k][tn * 4 + j];
#pragma unroll
            for (int i = 0; i < 4; i++)
#pragma unroll
                for (int j = 0; j < 4; j++) acc[i][j] += av[i] * bv[j];
        }
        __syncthreads();
    }
#pragma unroll
    for (int i = 0; i < 4; i++) {
        int gr = row0 + tm * 4 + i;
        if (gr >= nrows) continue;
#pragma unroll
        for (int j = 0; j < 4; j++) {
            int gc = colblk + tn * 4 + j;
            if (gc < ncols) C[(size_t)gr * ldc + gc] = acc[i][j];
        }
    }
}

// ---------------- helpers ----------------
__device__ __forceinline__ void store8h(f16* p, const float o[8]) {
    f16x8 v;
#pragma unroll
    for (int k = 0; k < 8; k++) v[k] = (f16)o[k];
    *(f16x8*)p = v;
}

__device__ __forceinline__ float dot8_lrelu(const uint4& vr, const f16x2 u2[4],
                                            const f16x2 a2[4]) {
    const f16x2* vp = (const f16x2*)&vr;
    float p = 0.f;
#pragma unroll
    for (int k = 0; k < 4; k++) {
        f16x2 w = u2[k] + vp[k];
        f16x2 lr = __builtin_elementwise_max(w, w * (_Float16)0.2f);
#if __has_builtin(__builtin_amdgcn_fdot2)
        p = __builtin_amdgcn_fdot2(lr, a2[k], p, false);
#else
        p = fmaf((float)lr[0], (float)a2[k][0], p);
        p = fmaf((float)lr[1], (float)a2[k][1], p);
#endif
    }
    return p;
}

// ---------------- layer-1 edge/aggregation: one wave per target, ALL 8 heads ----------------
// lane l serves head l>>3, dims (l&7)*8 .. +7; 2-deep software-pipelined gather.
__global__ void edge_l1(const int* __restrict__ offsets, const int* __restrict__ dsts,
                        const f16* __restrict__ h, const f16* __restrict__ uv,
                        const float* __restrict__ a, f16* __restrict__ x2, int n) {
    const int lane = threadIdx.x & 63;
    const int wave = threadIdx.x >> 6;
    const int t = blockIdx.x * (blockDim.x >> 6) + wave;
    if (t >= n) return;
    const int head = lane >> 3;
    const int sub = lane & 7;
    const unsigned voff = head * 128 + 64 + sub * 8;
    const unsigned uoff = head * 128 + sub * 8;
    const unsigned hoff = lane * 8;

    f16x2 u2[4], a2[4];
    {
        uint4 ur = *(const uint4*)(uv + (size_t)t * 1024 + uoff);
        const f16x2* up = (const f16x2*)&ur;
#pragma unroll
        for (int k = 0; k < 4; k++) u2[k] = up[k];
        const float4* ap = (const float4*)(a + hoff);
        float4 a0 = ap[0], a1 = ap[1];
        a2[0] = f16x2{(f16)a0.x, (f16)a0.y};
        a2[1] = f16x2{(f16)a0.z, (f16)a0.w};
        a2[2] = f16x2{(f16)a1.x, (f16)a1.y};
        a2[3] = f16x2{(f16)a1.z, (f16)a1.w};
    }

    const int s0 = offsets[t], s1 = offsets[t + 1];
    float acc[8] = {0.f, 0.f, 0.f, 0.f, 0.f, 0.f, 0.f, 0.f};
    float rs = 0.f;

    for (int base = s0; base < s1; base += 64) {
        int cnt = s1 - base;
        if (cnt > 64) cnt = 64;
        int myd = (lane < cnt) ? dsts[base + lane] : 0;
        // pipeline prologue
        int d0 = __shfl(myd, 0, 64);
        uint4 vr = *(const uint4*)(uv + (size_t)(unsigned)d0 * 1024 + voff);
        uint4 hr = *(const uint4*)(h + (size_t)(unsigned)d0 * 512 + hoff);
        for (int j = 0; j < cnt; j++) {
            uint4 vr_n, hr_n;
            if (j + 1 < cnt) {
                int dn = __shfl(myd, j + 1, 64);
                vr_n = *(const uint4*)(uv + (size_t)(unsigned)dn * 1024 + voff);
                hr_n = *(const uint4*)(h + (size_t)(unsigned)dn * 512 + hoff);
            }
            float p = dot8_lrelu(vr, u2, a2);
            p += __shfl_xor(p, 1, 64);
            p += __shfl_xor(p, 2, 64);
            p += __shfl_xor(p, 4, 64);
            float wgt = __expf(p);
            rs += wgt;
            const f16* hp = (const f16*)&hr;
#pragma unroll
            for (int k = 0; k < 8; k++) acc[k] = fmaf(wgt, (float)hp[k], acc[k]);
            vr = vr_n;
            hr = hr_n;
        }
    }
    float inv = 1.f / rs;
    float o[8];
#pragma unroll
    for (int k = 0; k < 8; k++) {
        float hp = acc[k] * inv;
        float e1 = hp > 0.f ? hp : expm1f(hp);
        o[k] = e1 > 0.f ? e1 : expm1f(e1);
    }
    store8h(x2 + (size_t)t * 512 + hoff, o);
}

// ---------------- layer-2 edge/aggregation (2-deep pipelined) ----------------
__global__ void edge_l2(const int* __restrict__ offsets, const int* __restrict__ dsts,
                        const float* __restrict__ h2, const float* __restrict__ uv2,
                        const float* __restrict__ a_out, float* __restrict__ out, int n) {
    int wave = threadIdx.x >> 6;
    int lane = threadIdx.x & 63;
    int t = blockIdx.x * (blockDim.x >> 6) + wave;
    if (t >= n) return;
    bool act = lane < 40;
    float u_t = act ? uv2[(size_t)t * 80 + lane] : 0.f;
    float a_l = act ? a_out[lane] : 0.f;
    int s0 = offsets[t], s1 = offsets[t + 1];
    float acc = 0.f, rs = 0.f;
    for (int base = s0; base < s1; base += 64) {
        int cnt = s1 - base;
        if (cnt > 64) cnt = 64;
        int myd = (lane < cnt) ? dsts[base + lane] : 0;
        int d0 = __shfl(myd, 0, 64);
        float vc = act ? uv2[(size_t)(unsigned)d0 * 80 + 40 + lane] : 0.f;
        float hc = act ? h2[(size_t)(unsigned)d0 * 40 + lane] : 0.f;
        for (int j = 0; j < cnt; j++) {
            float vn = 0.f, hn = 0.f;
            if (j + 1 < cnt) {
                int dn = __shfl(myd, j + 1, 64);
                if (act) {
                    vn = uv2[(size_t)(unsigned)dn * 80 + 40 + lane];
                    hn = h2[(size_t)(unsigned)dn * 40 + lane];
                }
            }
            float w = u_t + vc;
            float lr = fmaxf(w, 0.2f * w);
            float p = a_l * lr;
#pragma unroll
            for (int m = 32; m; m >>= 1) p += __shfl_xor(p, m, 64);
            float wgt = __expf(p);
            rs += wgt;
            acc = fmaf(wgt, hc, acc);
            vc = vn;
            hc = hn;
        }
    }
    if (act) {
        float hp = acc / rs;
        out[(size_t)t * 40 + lane] = hp > 0.f ? hp : expm1f(hp);
    }
}

// ---------------- launch ----------------
extern "C" void kernel_launch(void* const* d_in, const int* in_sizes, int n_in,
                              void* d_out, int out_size, void* d_ws, size_t ws_size,
                              hipStream_t stream) {
    const float* x         = (const float*)d_in[0];
    const int*   edge      = (const int*)d_in[1];
    const float* W         = (const float*)d_in[2];
    const float* W_pair    = (const float*)d_in[3];
    const float* a         = (const float*)d_in[4];
    const float* W_out     = (const float*)d_in[5];
    const float* W_pair_out= (const float*)d_in[6];
    const float* a_out     = (const float*)d_in[7];
    float* out = (float*)d_out;

    const int n  = in_sizes[0] / FEAT;   // 50000
    const int ne = in_sizes[1] / 2;      // 1,650,000
    const int* srcArr = edge;
    const int* dstArr = edge + ne;

    char* ws = (char*)d_ws;
    size_t off = 0;
    auto alloc = [&](size_t bytes) -> void* {
        void* p = ws + off;
        off = (off + bytes + 255) & ~(size_t)255;
        return p;
    };
    f16* h    = (f16*)alloc((size_t)n * 512 * sizeof(f16));      // [N][512]; later aliased by h2/uv2
    f16* uv   = (f16*)alloc((size_t)n * 1024 * sizeof(f16));     // [N][1024]
    f16* x2   = (f16*)alloc((size_t)n * 512 * sizeof(f16));      // [N][512]
    f16* Wh_t = (f16*)alloc(512 * 512 * sizeof(f16));
    f16* Bp_t = (f16*)alloc(8 * 128 * 64 * sizeof(f16));
    f16* Wo_t = (f16*)alloc(40 * 512 * sizeof(f16));
    float* B2p = (float*)alloc(40 * 80 * sizeof(float));
    int* counts  = (int*)alloc((size_t)n * sizeof(int));
    int* offsets = (int*)alloc((size_t)(n + 1) * sizeof(int));
    int* cursor  = (int*)alloc((size_t)n * sizeof(int));
    int* dsts    = (int*)alloc((size_t)ne * sizeof(int));
    float* h2  = (float*)h;                          // h dead after edge_l1
    float* uv2 = (float*)((char*)h + (size_t)n * 40 * sizeof(float));

    // CSR build
    hipMemsetAsync(counts, 0, (size_t)n * sizeof(int), stream);
    hist_kernel<<<2048, 256, 0, stream>>>(srcArr, counts, ne);
    scan_kernel<<<1, 1024, 0, stream>>>(counts, offsets, cursor, n);
    scatter_kernel<<<2048, 256, 0, stream>>>(srcArr, dstArr, cursor, dsts, ne);

    // weight packs
    pack_Wh<<<(512 * 512 + 255) / 256, 256, 0, stream>>>(W, Wh_t);
    pack_Bp<<<(8 * 128 * 64 + 255) / 256, 256, 0, stream>>>(W_pair, Bp_t);
    pack_Wo<<<(40 * 512 + 255) / 256, 256, 0, stream>>>(W_out, Wo_t);
    repack_wpo<<<(40 * 80 + 255) / 256, 256, 0, stream>>>(W_pair_out, B2p);

    const int mBlocks = (n + 127) / 128;   // 391

    // h = f16(x) @ Wh   [N,512] f16  (f32->f16 conversion fused into A staging)
    gemm_mfma<float, f16><<<dim3(mBlocks, 1, 4), 256, 0, stream>>>(
        x, 512, 0, 0, Wh_t, 0, 512, h, 512, 0, n, 512);

    // uv[:, head*128+c] = h[:, head*64 + k] @ Bp_t[head]   (K=64, per-head batch)
    gemm_mfma<f16, f16><<<dim3(mBlocks, 8, 1), 256, 0, stream>>>(
        h, 512, 0, 64, Bp_t, 128L * 64, 64, uv, 1024, 128, n, 128);

    // layer-1 edge phase -> x2
    edge_l1<<<dim3((n + 3) / 4), 256, 0, stream>>>(offsets, dsts, h, uv, a, x2, n);

    // h2 = x2 @ W_out  [N,40] f32 (aliases h)
    gemm_mfma<f16, float><<<dim3(mBlocks, 1, 1), 256, 0, stream>>>(
        x2, 512, 0, 0, Wo_t, 0, 512, h2, 40, 0, n, 40);

    // uv2 = h2 @ B2p  [N,80] f32
    gemm_kernel<<<dim3((n + 63) / 64, 1, 2), 256, 0, stream>>>(
        h2, 40, B2p, 80, uv2, 80, n, 40, 80);

    // layer-2 edge phase -> out
    edge_l2<<<dim3((n + 3) / 4), 256, 0, stream>>>(offsets, dsts, h2, uv2, a_out, out, n);
}

// Round 5
// 1136.127 us; speedup vs baseline: 1.0076x; 1.0076x over previous
//
#include <hip/hip_runtime.h>
#include <hip/hip_bf16.h>
#include <hip/hip_fp16.h>

typedef _Float16 f16;
typedef _Float16 f16x2 __attribute__((ext_vector_type(2)));
typedef _Float16 f16x8 __attribute__((ext_vector_type(8)));
typedef float f32x4 __attribute__((ext_vector_type(4)));

#define HEADS 8
#define HID 64
#define NCLS 40
#define FEAT 512

// ---------------- packing ----------------
// Wh_t[c][k] = W[c>>6][k][c&63], c in [0,512)   ([col][K] f16)
__global__ void pack_Wh(const float* __restrict__ W, f16* __restrict__ Wt) {
    int idx = blockIdx.x * blockDim.x + threadIdx.x;
    if (idx >= 512 * 512) return;
    int c = idx >> 9, k = idx & 511;
    Wt[idx] = (f16)W[(c >> 6) * 512 * 64 + k * 64 + (c & 63)];
}

// Bp_t[head][c][k] = W_pair[head][(c>>6)*64 + k][c&63], c in [0,128), k in [0,64)
__global__ void pack_Bp(const float* __restrict__ Wp, f16* __restrict__ Bt) {
    int idx = blockIdx.x * blockDim.x + threadIdx.x;
    if (idx >= 8 * 128 * 64) return;
    int head = idx >> 13, c = (idx >> 6) & 127, k = idx & 63;
    Bt[idx] = (f16)Wp[head * 8192 + ((c >> 6) * 64 + k) * 64 + (c & 63)];
}

// Wo_t[c][k] = W_out[k][c], c in [0,40)
__global__ void pack_Wo(const float* __restrict__ Wo, f16* __restrict__ Wt) {
    int idx = blockIdx.x * blockDim.x + threadIdx.x;
    if (idx >= 40 * 512) return;
    int c = idx >> 9, k = idx & 511;
    Wt[idx] = (f16)Wo[k * 40 + c];
}

// B2p[k][p*40+j] = W_pair_out[p*40+k][j]  (f32, for the tiny vector GEMM)
__global__ void repack_wpo(const float* __restrict__ Wpo, float* __restrict__ B2p) {
    int idx = blockIdx.x * blockDim.x + threadIdx.x;
    if (idx >= 40 * 80) return;
    int k = idx / 80;
    int c = idx % 80;
    int p = c / 40;
    int j = c % 40;
    B2p[idx] = Wpo[(p * 40 + k) * 40 + j];
}

// vh2[t][k] = {f16(v2[t][k]), f16(h2[t][k])}  — one 4B gather per lane in edge_l2
__global__ void pack_vh2(const float* __restrict__ h2, const float* __restrict__ uv2,
                         f16x2* __restrict__ vh2, int total) {
    int i = blockIdx.x * blockDim.x + threadIdx.x;
    if (i >= total) return;
    int t = i / 40, k = i % 40;
    vh2[i] = f16x2{(f16)uv2[(size_t)t * 80 + 40 + k], (f16)h2[i]};
}

// ---------------- CSR build (group edges by src == target row) ----------------
__global__ void hist_kernel(const int* __restrict__ src, int* __restrict__ counts, int ne) {
    int i = blockIdx.x * blockDim.x + threadIdx.x;
    int stride = gridDim.x * blockDim.x;
    for (; i < ne; i += stride) atomicAdd(&counts[src[i]], 1);
}

__global__ void scan_kernel(const int* __restrict__ counts, int* __restrict__ offsets,
                            int* __restrict__ cursor, int n) {
    __shared__ int part[1024];
    int tid = threadIdx.x;
    int chunk = (n + 1023) >> 10;
    int begin = tid * chunk;
    int end = begin + chunk;
    if (end > n) end = n;
    int s = 0;
    for (int i = begin; i < end; i++) s += counts[i];
    part[tid] = s;
    __syncthreads();
    for (int d = 1; d < 1024; d <<= 1) {
        int v = 0;
        if (tid >= d) v = part[tid - d];
        __syncthreads();
        if (tid >= d) part[tid] += v;
        __syncthreads();
    }
    int run = (tid == 0) ? 0 : part[tid - 1];
    for (int i = begin; i < end; i++) {
        cursor[i] = run;
        run += counts[i];
        offsets[i + 1] = run;
    }
    if (tid == 0) offsets[0] = 0;
}

__global__ void scatter_kernel(const int* __restrict__ src, const int* __restrict__ dst,
                               int* __restrict__ cursor, int* __restrict__ dsts, int ne) {
    int i = blockIdx.x * blockDim.x + threadIdx.x;
    int stride = gridDim.x * blockDim.x;
    for (; i < ne; i += stride) {
        int pos = atomicAdd(&cursor[src[i]], 1);
        dsts[pos] = dst[i];
    }
}

// ---------------- MFMA f16 GEMM: 128x128 tile, BK=32, 4 waves ----------------
__device__ __forceinline__ void stC(float* p, float v) { *p = v; }
__device__ __forceinline__ void stC(f16* p, float v) { *p = (f16)v; }
__device__ __forceinline__ f16x8 ldA8(const f16* p) { return *(const f16x8*)p; }
__device__ __forceinline__ f16x8 ldA8(const float* p) {
    float4 a = ((const float4*)p)[0];
    float4 b = ((const float4*)p)[1];
    f16x8 r = {(f16)a.x, (f16)a.y, (f16)a.z, (f16)a.w, (f16)b.x, (f16)b.y, (f16)b.z, (f16)b.w};
    return r;
}

// A [M][lda] (cols a0.. a0+K), Bt [batch][ncols][K] f16 (transposed), C [M][ldc]
template <typename AT, typename CT>
__global__ __launch_bounds__(256)
void gemm_mfma(const AT* __restrict__ A, int lda, int acol0, int acolStride,
               const f16* __restrict__ Bt, long bBatchStride, int K,
               CT* __restrict__ C, int ldc, int ccolStride,
               int nrows, int ncols) {
    __shared__ f16 As[128][40];   // BK=32 padded to 40 (80B rows -> 2-way max on b128 reads)
    __shared__ f16 Bs[128][40];
    const int batch = blockIdx.y;
    const int row0 = blockIdx.x * 128;
    const int col0 = blockIdx.z * 128;
    const int a0 = acol0 + batch * acolStride;
    const f16* Bb = Bt + (size_t)batch * bBatchStride;
    const int tid = threadIdx.x;
    const int lane = tid & 63;
    const int wave = tid >> 6;
    const int wr = (wave >> 1) * 64;
    const int wc = (wave & 1) * 64;
    f32x4 acc[4][4] = {};

    for (int k0 = 0; k0 < K; k0 += 32) {
#pragma unroll
        for (int i = 0; i < 2; i++) {
            int idx = tid + i * 256;
            int r = idx >> 2, ch = idx & 3;
            int gr = row0 + r;
            f16x8 val = {};
            if (gr < nrows) val = ldA8(A + (size_t)gr * lda + a0 + k0 + ch * 8);
            *(f16x8*)(&As[r][ch * 8]) = val;
        }
#pragma unroll
        for (int i = 0; i < 2; i++) {
            int idx = tid + i * 256;
            int r = idx >> 2, ch = idx & 3;
            int gc = col0 + r;
            f16x8 val = {};
            if (gc < ncols) val = *(const f16x8*)(Bb + (size_t)gc * K + k0 + ch * 8);
            *(f16x8*)(&Bs[r][ch * 8]) = val;
        }
        __syncthreads();
        f16x8 af[4], bf[4];
#pragma unroll
        for (int t = 0; t < 4; t++)
            af[t] = *(const f16x8*)(&As[wr + t * 16 + (lane & 15)][(lane >> 4) * 8]);
#pragma unroll
        for (int t = 0; t < 4; t++)
            bf[t] = *(const f16x8*)(&Bs[wc + t * 16 + (lane & 15)][(lane >> 4) * 8]);
#pragma unroll
        for (int i = 0; i < 4; i++)
#pragma unroll
            for (int j = 0; j < 4; j++)
                acc[i][j] = __builtin_amdgcn_mfma_f32_16x16x32_f16(af[i], bf[j], acc[i][j], 0, 0, 0);
        __syncthreads();
    }
    // C/D layout: col = lane&15, row = (lane>>4)*4 + r   [HW-verified]
    const int crow = (lane >> 4) * 4;
    const int ccol = lane & 15;
#pragma unroll
    for (int i = 0; i < 4; i++) {
#pragma unroll
        for (int j = 0; j < 4; j++) {
            int gc = col0 + wc + j * 16 + ccol;
            if (gc >= ncols) continue;
#pragma unroll
            for (int r = 0; r < 4; r++) {
                int gr = row0 + wr + i * 16 + crow + r;
                if (gr < nrows)
                    stC(&C[(size_t)gr * ldc + (size_t)batch * ccolStride + gc], acc[i][j][r]);
            }
        }
    }
}

// ---------------- tiny fp32 vector GEMM (kept for uv2: K=40, N=80) ----------------
__global__ void gemm_kernel(const float* __restrict__ A, int lda,
                            const float* __restrict__ B, int ldb,
                            float* __restrict__ C, int ldc,
                            int nrows, int K, int ncols) {
    __shared__ __align__(16) float As[16][68];
    __shared__ __align__(16) float Bs[16][64];
    const int colblk = blockIdx.z * 64;
    const int row0 = blockIdx.x * 64;
    const int tid = threadIdx.x;
    const int tm = tid >> 4, tn = tid & 15;
    float acc[4][4] = {};
    for (int k0 = 0; k0 < K; k0 += 16) {
#pragma unroll
        for (int i = 0; i < 4; i++) {
            int idx = tid + i * 256;
            int m = idx >> 4;
            int k = idx & 15;
            int gr = row0 + m;
            float v = 0.f;
            if (gr < nrows && (k0 + k) < K) v = A[(size_t)gr * lda + k0 + k];
            As[k][m] = v;
        }
#pragma unroll
        for (int i = 0; i < 4; i++) {
            int idx = tid + i * 256;
            int k = idx >> 6;
            int j = idx & 63;
            float v = 0.f;
            if ((k0 + k) < K && (colblk + j) < ncols) v = B[(size_t)(k0 + k) * ldb + colblk + j];
            Bs[k][j] = v;
        }
        __syncthreads();
#pragma unroll
        for (int k = 0; k < 16; k++) {
            float av[4], bv[4];
#pragma unroll
            for (int i = 0; i < 4; i++) av[i] = As[k][tm * 4 + i];
#pragma unroll
            for (int j = 0; j < 4; j++) bv[j] = Bs[k][tn * 4 + j];
#pragma unroll
            for (int i = 0; i < 4; i++)
#pragma unroll
                for (int j = 0; j < 4; j++) acc[i][j] += av[i] * bv[j];
        }
        __syncthreads();
    }
#pragma unroll
    for (int i = 0; i < 4; i++) {
        int gr = row0 + tm * 4 + i;
        if (gr >= nrows) continue;
#pragma unroll
        for (int j = 0; j < 4; j++) {
            int gc = colblk + tn * 4 + j;
            if (gc < ncols) C[(size_t)gr * ldc + gc] = acc[i][j];
        }
    }
}

// ---------------- helpers ----------------
__device__ __forceinline__ void store8h(f16* p, const float o[8]) {
    f16x8 v;
#pragma unroll
    for (int k = 0; k < 8; k++) v[k] = (f16)o[k];
    *(f16x8*)p = v;
}

__device__ __forceinline__ float dot8_lrelu(const uint4& vr, const f16x2 u2[4],
                                            const f16x2 a2[4]) {
    const f16x2* vp = (const f16x2*)&vr;
    float p = 0.f;
#pragma unroll
    for (int k = 0; k < 4; k++) {
        f16x2 w = u2[k] + vp[k];
        f16x2 lr = __builtin_elementwise_max(w, w * (_Float16)0.2f);
#if __has_builtin(__builtin_amdgcn_fdot2)
        p = __builtin_amdgcn_fdot2(lr, a2[k], p, false);
#else
        p = fmaf((float)lr[0], (float)a2[k][0], p);
        p = fmaf((float)lr[1], (float)a2[k][1], p);
#endif
    }
    return p;
}

// ---------------- layer-1 edge/aggregation: one wave per target, ALL 8 heads ----------------
// lane l serves head l>>3, dims (l&7)*8 .. +7; 3-deep software-pipelined gather.
__global__ void edge_l1(const int* __restrict__ offsets, const int* __restrict__ dsts,
                        const f16* __restrict__ h, const f16* __restrict__ uv,
                        const float* __restrict__ a, f16* __restrict__ x2, int n) {
    const int lane = threadIdx.x & 63;
    const int wave = threadIdx.x >> 6;
    const int t = blockIdx.x * (blockDim.x >> 6) + wave;
    if (t >= n) return;
    const int head = lane >> 3;
    const int sub = lane & 7;
    const unsigned voff = head * 128 + 64 + sub * 8;
    const unsigned uoff = head * 128 + sub * 8;
    const unsigned hoff = lane * 8;

    f16x2 u2[4], a2[4];
    {
        uint4 ur = *(const uint4*)(uv + (size_t)t * 1024 + uoff);
        const f16x2* up = (const f16x2*)&ur;
#pragma unroll
        for (int k = 0; k < 4; k++) u2[k] = up[k];
        const float4* ap = (const float4*)(a + hoff);
        float4 a0 = ap[0], a1 = ap[1];
        a2[0] = f16x2{(f16)a0.x, (f16)a0.y};
        a2[1] = f16x2{(f16)a0.z, (f16)a0.w};
        a2[2] = f16x2{(f16)a1.x, (f16)a1.y};
        a2[3] = f16x2{(f16)a1.z, (f16)a1.w};
    }

    const int s0 = offsets[t], s1 = offsets[t + 1];
    float acc[8] = {0.f, 0.f, 0.f, 0.f, 0.f, 0.f, 0.f, 0.f};
    float rs = 0.f;

    for (int base = s0; base < s1; base += 64) {
        int cnt = s1 - base;
        if (cnt > 64) cnt = 64;
        int myd = (lane < cnt) ? dsts[base + lane] : 0;
        // 3-deep pipeline prologue
        int d0 = __shfl(myd, 0, 64);
        uint4 vr0 = *(const uint4*)(uv + (size_t)(unsigned)d0 * 1024 + voff);
        uint4 hr0 = *(const uint4*)(h + (size_t)(unsigned)d0 * 512 + hoff);
        uint4 vr1, hr1;
        if (cnt > 1) {
            int d1 = __shfl(myd, 1, 64);
            vr1 = *(const uint4*)(uv + (size_t)(unsigned)d1 * 1024 + voff);
            hr1 = *(const uint4*)(h + (size_t)(unsigned)d1 * 512 + hoff);
        }
        for (int j = 0; j < cnt; j++) {
            uint4 vr2, hr2;
            if (j + 2 < cnt) {
                int d2 = __shfl(myd, j + 2, 64);
                vr2 = *(const uint4*)(uv + (size_t)(unsigned)d2 * 1024 + voff);
                hr2 = *(const uint4*)(h + (size_t)(unsigned)d2 * 512 + hoff);
            }
            float p = dot8_lrelu(vr0, u2, a2);
            p += __shfl_xor(p, 1, 64);
            p += __shfl_xor(p, 2, 64);
            p += __shfl_xor(p, 4, 64);
            float wgt = __expf(p);
            rs += wgt;
            const f16* hp = (const f16*)&hr0;
#pragma unroll
            for (int k = 0; k < 8; k++) acc[k] = fmaf(wgt, (float)hp[k], acc[k]);
            vr0 = vr1; hr0 = hr1;
            vr1 = vr2; hr1 = hr2;
        }
    }
    float inv = 1.f / rs;
    float o[8];
#pragma unroll
    for (int k = 0; k < 8; k++) {
        float hp = acc[k] * inv;
        float e1 = hp > 0.f ? hp : expm1f(hp);
        o[k] = e1 > 0.f ? e1 : expm1f(e1);
    }
    store8h(x2 + (size_t)t * 512 + hoff, o);
}

// ---------------- layer-2 edge/aggregation: one 4B gather per lane per edge ----------------
// vh2[d][k] = {v2, h2} f16 pairs; u2 read from uv2 (f32) once per target.
__global__ void edge_l2(const int* __restrict__ offsets, const int* __restrict__ dsts,
                        const f16x2* __restrict__ vh2, const float* __restrict__ uv2,
                        const float* __restrict__ a_out, float* __restrict__ out, int n) {
    int wave = threadIdx.x >> 6;
    int lane = threadIdx.x & 63;
    int t = blockIdx.x * (blockDim.x >> 6) + wave;
    if (t >= n) return;
    bool act = lane < 40;
    float u_t = act ? uv2[(size_t)t * 80 + lane] : 0.f;
    float a_l = act ? a_out[lane] : 0.f;
    int s0 = offsets[t], s1 = offsets[t + 1];
    float acc = 0.f, rs = 0.f;
    const f16x2 z2 = {(_Float16)0.f, (_Float16)0.f};
    for (int base = s0; base < s1; base += 64) {
        int cnt = s1 - base;
        if (cnt > 64) cnt = 64;
        int myd = (lane < cnt) ? dsts[base + lane] : 0;
        int d0 = __shfl(myd, 0, 64);
        f16x2 vh0 = act ? vh2[(size_t)(unsigned)d0 * 40 + lane] : z2;
        f16x2 vh1 = z2;
        if (cnt > 1) {
            int d1 = __shfl(myd, 1, 64);
            vh1 = act ? vh2[(size_t)(unsigned)d1 * 40 + lane] : z2;
        }
        for (int j = 0; j < cnt; j++) {
            f16x2 vh2n = z2;
            if (j + 2 < cnt) {
                int dn = __shfl(myd, j + 2, 64);
                vh2n = act ? vh2[(size_t)(unsigned)dn * 40 + lane] : z2;
            }
            float w = u_t + (float)vh0[0];
            float lr = fmaxf(w, 0.2f * w);
            float p = a_l * lr;
#pragma unroll
            for (int m = 32; m; m >>= 1) p += __shfl_xor(p, m, 64);
            float wgt = __expf(p);
            rs += wgt;
            acc = fmaf(wgt, (float)vh0[1], acc);
            vh0 = vh1;
            vh1 = vh2n;
        }
    }
    if (act) {
        float hp = acc / rs;
        out[(size_t)t * 40 + lane] = hp > 0.f ? hp : expm1f(hp);
    }
}

// ---------------- launch ----------------
extern "C" void kernel_launch(void* const* d_in, const int* in_sizes, int n_in,
                              void* d_out, int out_size, void* d_ws, size_t ws_size,
                              hipStream_t stream) {
    const float* x         = (const float*)d_in[0];
    const int*   edge      = (const int*)d_in[1];
    const float* W         = (const float*)d_in[2];
    const float* W_pair    = (const float*)d_in[3];
    const float* a         = (const float*)d_in[4];
    const float* W_out     = (const float*)d_in[5];
    const float* W_pair_out= (const float*)d_in[6];
    const float* a_out     = (const float*)d_in[7];
    float* out = (float*)d_out;

    const int n  = in_sizes[0] / FEAT;   // 50000
    const int ne = in_sizes[1] / 2;      // 1,650,000
    const int* srcArr = edge;
    const int* dstArr = edge + ne;

    char* ws = (char*)d_ws;
    size_t off = 0;
    auto alloc = [&](size_t bytes) -> void* {
        void* p = ws + off;
        off = (off + bytes + 255) & ~(size_t)255;
        return p;
    };
    f16* h    = (f16*)alloc((size_t)n * 512 * sizeof(f16));      // [N][512]; later aliased by h2/uv2
    f16* uv   = (f16*)alloc((size_t)n * 1024 * sizeof(f16));     // [N][1024]
    f16* x2   = (f16*)alloc((size_t)n * 512 * sizeof(f16));      // [N][512]
    f16x2* vh2 = (f16x2*)alloc((size_t)n * 40 * sizeof(f16x2));  // [N][40] {v2,h2}
    f16* Wh_t = (f16*)alloc(512 * 512 * sizeof(f16));
    f16* Bp_t = (f16*)alloc(8 * 128 * 64 * sizeof(f16));
    f16* Wo_t = (f16*)alloc(40 * 512 * sizeof(f16));
    float* B2p = (float*)alloc(40 * 80 * sizeof(float));
    int* counts  = (int*)alloc((size_t)n * sizeof(int));
    int* offsets = (int*)alloc((size_t)(n + 1) * sizeof(int));
    int* cursor  = (int*)alloc((size_t)n * sizeof(int));
    int* dsts    = (int*)alloc((size_t)ne * sizeof(int));
    float* h2  = (float*)h;                          // h dead after edge_l1
    float* uv2 = (float*)((char*)h + (size_t)n * 40 * sizeof(float));

    // CSR build
    hipMemsetAsync(counts, 0, (size_t)n * sizeof(int), stream);
    hist_kernel<<<2048, 256, 0, stream>>>(srcArr, counts, ne);
    scan_kernel<<<1, 1024, 0, stream>>>(counts, offsets, cursor, n);
    scatter_kernel<<<2048, 256, 0, stream>>>(srcArr, dstArr, cursor, dsts, ne);

    // weight packs
    pack_Wh<<<(512 * 512 + 255) / 256, 256, 0, stream>>>(W, Wh_t);
    pack_Bp<<<(8 * 128 * 64 + 255) / 256, 256, 0, stream>>>(W_pair, Bp_t);
    pack_Wo<<<(40 * 512 + 255) / 256, 256, 0, stream>>>(W_out, Wo_t);
    repack_wpo<<<(40 * 80 + 255) / 256, 256, 0, stream>>>(W_pair_out, B2p);

    const int mBlocks = (n + 127) / 128;   // 391

    // h = f16(x) @ Wh   [N,512] f16  (f32->f16 conversion fused into A staging)
    gemm_mfma<float, f16><<<dim3(mBlocks, 1, 4), 256, 0, stream>>>(
        x, 512, 0, 0, Wh_t, 0, 512, h, 512, 0, n, 512);

    // uv[:, head*128+c] = h[:, head*64 + k] @ Bp_t[head]   (K=64, per-head batch)
    gemm_mfma<f16, f16><<<dim3(mBlocks, 8, 1), 256, 0, stream>>>(
        h, 512, 0, 64, Bp_t, 128L * 64, 64, uv, 1024, 128, n, 128);

    // layer-1 edge phase -> x2
    edge_l1<<<dim3((n + 3) / 4), 256, 0, stream>>>(offsets, dsts, h, uv, a, x2, n);

    // h2 = x2 @ W_out  [N,40] f32 (aliases h)
    gemm_mfma<f16, float><<<dim3(mBlocks, 1, 1), 256, 0, stream>>>(
        x2, 512, 0, 0, Wo_t, 0, 512, h2, 40, 0, n, 40);

    // uv2 = h2 @ B2p  [N,80] f32
    gemm_kernel<<<dim3((n + 63) / 64, 1, 2), 256, 0, stream>>>(
        h2, 40, B2p, 80, uv2, 80, n, 40, 80);

    // pack interleaved {v2,h2} f16 pairs for single-gather edge_l2
    pack_vh2<<<(n * 40 + 255) / 256, 256, 0, stream>>>(h2, uv2, vh2, n * 40);

    // layer-2 edge phase -> out
    edge_l2<<<dim3((n + 3) / 4), 256, 0, stream>>>(offsets, dsts, vh2, uv2, a_out, out, n);
}

// Round 6
// 1062.972 us; speedup vs baseline: 1.0769x; 1.0688x over previous
//
#include <hip/hip_runtime.h>
#include <hip/hip_bf16.h>
#include <hip/hip_fp16.h>

typedef _Float16 f16;
typedef _Float16 f16x2 __attribute__((ext_vector_type(2)));
typedef _Float16 f16x8 __attribute__((ext_vector_type(8)));
typedef float f32x4 __attribute__((ext_vector_type(4)));

#define HEADS 8
#define HID 64
#define NCLS 40
#define FEAT 512

// ---------------- packing ----------------
// Wh_t[c][k] = W[c>>6][k][c&63], c in [0,512)   ([col][K] f16)
__global__ void pack_Wh(const float* __restrict__ W, f16* __restrict__ Wt) {
    int idx = blockIdx.x * blockDim.x + threadIdx.x;
    if (idx >= 512 * 512) return;
    int c = idx >> 9, k = idx & 511;
    Wt[idx] = (f16)W[(c >> 6) * 512 * 64 + k * 64 + (c & 63)];
}

// Bp_t[head][c][k] = W_pair[head][(c>>6)*64 + k][c&63], c in [0,128), k in [0,64)
__global__ void pack_Bp(const float* __restrict__ Wp, f16* __restrict__ Bt) {
    int idx = blockIdx.x * blockDim.x + threadIdx.x;
    if (idx >= 8 * 128 * 64) return;
    int head = idx >> 13, c = (idx >> 6) & 127, k = idx & 63;
    Bt[idx] = (f16)Wp[head * 8192 + ((c >> 6) * 64 + k) * 64 + (c & 63)];
}

// Wo_t[c][k] = W_out[k][c], c in [0,40)
__global__ void pack_Wo(const float* __restrict__ Wo, f16* __restrict__ Wt) {
    int idx = blockIdx.x * blockDim.x + threadIdx.x;
    if (idx >= 40 * 512) return;
    int c = idx >> 9, k = idx & 511;
    Wt[idx] = (f16)Wo[k * 40 + c];
}

// B2p[k][p*40+j] = W_pair_out[p*40+k][j]  (f32, for the tiny vector GEMM)
__global__ void repack_wpo(const float* __restrict__ Wpo, float* __restrict__ B2p) {
    int idx = blockIdx.x * blockDim.x + threadIdx.x;
    if (idx >= 40 * 80) return;
    int k = idx / 80;
    int c = idx % 80;
    int p = c / 40;
    int j = c % 40;
    B2p[idx] = Wpo[(p * 40 + k) * 40 + j];
}

// vh2[t][k] = {f16(v2[t][k]), f16(h2[t][k])}  — one 4B gather per lane in edge_l2
__global__ void pack_vh2(const float* __restrict__ h2, const float* __restrict__ uv2,
                         f16x2* __restrict__ vh2, int total) {
    int i = blockIdx.x * blockDim.x + threadIdx.x;
    if (i >= total) return;
    int t = i / 40, k = i % 40;
    vh2[i] = f16x2{(f16)uv2[(size_t)t * 80 + 40 + k], (f16)h2[i]};
}

// ---------------- CSR build (group edges by src == target row) ----------------
__global__ void hist_kernel(const int* __restrict__ src, int* __restrict__ counts, int ne) {
    int i = blockIdx.x * blockDim.x + threadIdx.x;
    int stride = gridDim.x * blockDim.x;
    for (; i < ne; i += stride) atomicAdd(&counts[src[i]], 1);
}

// hierarchical exclusive scan: partial sums (196 blocks) -> top scan (1 block) -> final
__global__ void scan_partial(const int* __restrict__ counts, int* __restrict__ partial, int n) {
    __shared__ int s[256];
    int i = blockIdx.x * 256 + threadIdx.x;
    s[threadIdx.x] = (i < n) ? counts[i] : 0;
    __syncthreads();
    for (int d = 128; d > 0; d >>= 1) {
        if (threadIdx.x < d) s[threadIdx.x] += s[threadIdx.x + d];
        __syncthreads();
    }
    if (threadIdx.x == 0) partial[blockIdx.x] = s[0];
}

__global__ void scan_top(int* __restrict__ partial, int nb) {
    __shared__ int s[1024];
    int tid = threadIdx.x;
    s[tid] = (tid < nb) ? partial[tid] : 0;
    __syncthreads();
    for (int d = 1; d < 1024; d <<= 1) {
        int v = (tid >= d) ? s[tid - d] : 0;
        __syncthreads();
        s[tid] += v;
        __syncthreads();
    }
    if (tid < nb) partial[tid] = (tid == 0) ? 0 : s[tid - 1];  // exclusive
}

__global__ void scan_final(const int* __restrict__ counts, const int* __restrict__ partialEx,
                           int* __restrict__ offsets, int* __restrict__ cursor, int n) {
    __shared__ int s[256];
    int i = blockIdx.x * 256 + threadIdx.x;
    int v = (i < n) ? counts[i] : 0;
    s[threadIdx.x] = v;
    __syncthreads();
    for (int d = 1; d < 256; d <<= 1) {
        int u = (threadIdx.x >= d) ? s[threadIdx.x - d] : 0;
        __syncthreads();
        s[threadIdx.x] += u;
        __syncthreads();
    }
    int excl = partialEx[blockIdx.x] + s[threadIdx.x] - v;
    if (i < n) {
        cursor[i] = excl;
        offsets[i] = excl;
        if (i == n - 1) offsets[n] = excl + v;
    }
}

__global__ void scatter_kernel(const int* __restrict__ src, const int* __restrict__ dst,
                               int* __restrict__ cursor, int* __restrict__ dsts, int ne) {
    int i = blockIdx.x * blockDim.x + threadIdx.x;
    int stride = gridDim.x * blockDim.x;
    for (; i < ne; i += stride) {
        int pos = atomicAdd(&cursor[src[i]], 1);
        dsts[pos] = dst[i];
    }
}

// sort each target's adjacency (per 64-chunk) by source id: device-wide lockstep
// waves then sweep sources in increasing order -> L2-sized hot window.
__global__ void sort_dsts(const int* __restrict__ offsets, int* __restrict__ dsts, int n) {
    int wave = threadIdx.x >> 6, lane = threadIdx.x & 63;
    int t = blockIdx.x * (blockDim.x >> 6) + wave;
    if (t >= n) return;
    int s0 = offsets[t], s1 = offsets[t + 1];
    for (int base = s0; base < s1; base += 64) {
        int cnt = s1 - base;
        if (cnt > 64) cnt = 64;
        int v = (lane < cnt) ? dsts[base + lane] : 0x7fffffff;
#pragma unroll
        for (int k = 2; k <= 64; k <<= 1) {
#pragma unroll
            for (int j = k >> 1; j > 0; j >>= 1) {
                int o = __shfl_xor(v, j, 64);
                bool lower = (lane & j) == 0;
                bool asc = (lane & k) == 0;
                int mn = min(v, o), mx = max(v, o);
                v = (lower == asc) ? mn : mx;
            }
        }
        if (lane < cnt) dsts[base + lane] = v;
    }
}

// ---------------- MFMA f16 GEMM: 128x128 tile, BK=32, 4 waves ----------------
__device__ __forceinline__ void stC(float* p, float v) { *p = v; }
__device__ __forceinline__ void stC(f16* p, float v) { *p = (f16)v; }
__device__ __forceinline__ f16x8 ldA8(const f16* p) { return *(const f16x8*)p; }
__device__ __forceinline__ f16x8 ldA8(const float* p) {
    float4 a = ((const float4*)p)[0];
    float4 b = ((const float4*)p)[1];
    f16x8 r = {(f16)a.x, (f16)a.y, (f16)a.z, (f16)a.w, (f16)b.x, (f16)b.y, (f16)b.z, (f16)b.w};
    return r;
}

// A [M][lda] (cols a0.. a0+K), Bt [batch][ncols][K] f16 (transposed), C [M][ldc]
template <typename AT, typename CT>
__global__ __launch_bounds__(256)
void gemm_mfma(const AT* __restrict__ A, int lda, int acol0, int acolStride,
               const f16* __restrict__ Bt, long bBatchStride, int K,
               CT* __restrict__ C, int ldc, int ccolStride,
               int nrows, int ncols) {
    __shared__ f16 As[128][40];   // BK=32 padded to 40 (80B rows -> 2-way max on b128 reads)
    __shared__ f16 Bs[128][40];
    const int batch = blockIdx.y;
    const int row0 = blockIdx.x * 128;
    const int col0 = blockIdx.z * 128;
    const int a0 = acol0 + batch * acolStride;
    const f16* Bb = Bt + (size_t)batch * bBatchStride;
    const int tid = threadIdx.x;
    const int lane = tid & 63;
    const int wave = tid >> 6;
    const int wr = (wave >> 1) * 64;
    const int wc = (wave & 1) * 64;
    f32x4 acc[4][4] = {};

    for (int k0 = 0; k0 < K; k0 += 32) {
#pragma unroll
        for (int i = 0; i < 2; i++) {
            int idx = tid + i * 256;
            int r = idx >> 2, ch = idx & 3;
            int gr = row0 + r;
            f16x8 val = {};
            if (gr < nrows) val = ldA8(A + (size_t)gr * lda + a0 + k0 + ch * 8);
            *(f16x8*)(&As[r][ch * 8]) = val;
        }
#pragma unroll
        for (int i = 0; i < 2; i++) {
            int idx = tid + i * 256;
            int r = idx >> 2, ch = idx & 3;
            int gc = col0 + r;
            f16x8 val = {};
            if (gc < ncols) val = *(const f16x8*)(Bb + (size_t)gc * K + k0 + ch * 8);
            *(f16x8*)(&Bs[r][ch * 8]) = val;
        }
        __syncthreads();
        f16x8 af[4], bf[4];
#pragma unroll
        for (int t = 0; t < 4; t++)
            af[t] = *(const f16x8*)(&As[wr + t * 16 + (lane & 15)][(lane >> 4) * 8]);
#pragma unroll
        for (int t = 0; t < 4; t++)
            bf[t] = *(const f16x8*)(&Bs[wc + t * 16 + (lane & 15)][(lane >> 4) * 8]);
#pragma unroll
        for (int i = 0; i < 4; i++)
#pragma unroll
            for (int j = 0; j < 4; j++)
                acc[i][j] = __builtin_amdgcn_mfma_f32_16x16x32_f16(af[i], bf[j], acc[i][j], 0, 0, 0);
        __syncthreads();
    }
    // C/D layout: col = lane&15, row = (lane>>4)*4 + r   [HW-verified]
    const int crow = (lane >> 4) * 4;
    const int ccol = lane & 15;
#pragma unroll
    for (int i = 0; i < 4; i++) {
#pragma unroll
        for (int j = 0; j < 4; j++) {
            int gc = col0 + wc + j * 16 + ccol;
            if (gc >= ncols) continue;
#pragma unroll
            for (int r = 0; r < 4; r++) {
                int gr = row0 + wr + i * 16 + crow + r;
                if (gr < nrows)
                    stC(&C[(size_t)gr * ldc + (size_t)batch * ccolStride + gc], acc[i][j][r]);
            }
        }
    }
}

// ---------------- tiny fp32 vector GEMM (kept for uv2: K=40, N=80) ----------------
__global__ void gemm_kernel(const float* __restrict__ A, int lda,
                            const float* __restrict__ B, int ldb,
                            float* __restrict__ C, int ldc,
                            int nrows, int K, int ncols) {
    __shared__ __align__(16) float As[16][68];
    __shared__ __align__(16) float Bs[16][64];
    const int colblk = blockIdx.z * 64;
    const int row0 = blockIdx.x * 64;
    const int tid = threadIdx.x;
    const int tm = tid >> 4, tn = tid & 15;
    float acc[4][4] = {};
    for (int k0 = 0; k0 < K; k0 += 16) {
#pragma unroll
        for (int i = 0; i < 4; i++) {
            int idx = tid + i * 256;
            int m = idx >> 4;
            int k = idx & 15;
            int gr = row0 + m;
            float v = 0.f;
            if (gr < nrows && (k0 + k) < K) v = A[(size_t)gr * lda + k0 + k];
            As[k][m] = v;
        }
#pragma unroll
        for (int i = 0; i < 4; i++) {
            int idx = tid + i * 256;
            int k = idx >> 6;
            int j = idx & 63;
            float v = 0.f;
            if ((k0 + k) < K && (colblk + j) < ncols) v = B[(size_t)(k0 + k) * ldb + colblk + j];
            Bs[k][j] = v;
        }
        __syncthreads();
#pragma unroll
        for (int k = 0; k < 16; k++) {
            float av[4], bv[4];
#pragma unroll
            for (int i = 0; i < 4; i++) av[i] = As[k][tm * 4 + i];
#pragma unroll
            for (int j = 0; j < 4; j++) bv[j] = Bs[k][tn * 4 + j];
#pragma unroll
            for (int i = 0; i < 4; i++)
#pragma unroll
                for (int j = 0; j < 4; j++) acc[i][j] += av[i] * bv[j];
        }
        __syncthreads();
    }
#pragma unroll
    for (int i = 0; i < 4; i++) {
        int gr = row0 + tm * 4 + i;
        if (gr >= nrows) continue;
#pragma unroll
        for (int j = 0; j < 4; j++) {
            int gc = colblk + tn * 4 + j;
            if (gc < ncols) C[(size_t)gr * ldc + gc] = acc[i][j];
        }
    }
}

// ---------------- helpers ----------------
__device__ __forceinline__ void store8h(f16* p, const float o[8]) {
    f16x8 v;
#pragma unroll
    for (int k = 0; k < 8; k++) v[k] = (f16)o[k];
    *(f16x8*)p = v;
}

__device__ __forceinline__ float dot8_lrelu(const uint4& vr, const f16x2 u2[4],
                                            const f16x2 a2[4]) {
    const f16x2* vp = (const f16x2*)&vr;
    float p = 0.f;
#pragma unroll
    for (int k = 0; k < 4; k++) {
        f16x2 w = u2[k] + vp[k];
        f16x2 lr = __builtin_elementwise_max(w, w * (_Float16)0.2f);
#if __has_builtin(__builtin_amdgcn_fdot2)
        p = __builtin_amdgcn_fdot2(lr, a2[k], p, false);
#else
        p = fmaf((float)lr[0], (float)a2[k][0], p);
        p = fmaf((float)lr[1], (float)a2[k][1], p);
#endif
    }
    return p;
}

// ---------------- layer-1 edge/aggregation: one wave per target, ALL 8 heads ----------------
// lane l serves head l>>3, dims (l&7)*8 .. +7; 2-deep software-pipelined gather.
__global__ void edge_l1(const int* __restrict__ offsets, const int* __restrict__ dsts,
                        const f16* __restrict__ h, const f16* __restrict__ uv,
                        const float* __restrict__ a, f16* __restrict__ x2, int n) {
    const int lane = threadIdx.x & 63;
    const int wave = threadIdx.x >> 6;
    const int t = blockIdx.x * (blockDim.x >> 6) + wave;
    if (t >= n) return;
    const int head = lane >> 3;
    const int sub = lane & 7;
    const unsigned voff = head * 128 + 64 + sub * 8;
    const unsigned uoff = head * 128 + sub * 8;
    const unsigned hoff = lane * 8;

    f16x2 u2[4], a2[4];
    {
        uint4 ur = *(const uint4*)(uv + (size_t)t * 1024 + uoff);
        const f16x2* up = (const f16x2*)&ur;
#pragma unroll
        for (int k = 0; k < 4; k++) u2[k] = up[k];
        const float4* ap = (const float4*)(a + hoff);
        float4 a0 = ap[0], a1 = ap[1];
        a2[0] = f16x2{(f16)a0.x, (f16)a0.y};
        a2[1] = f16x2{(f16)a0.z, (f16)a0.w};
        a2[2] = f16x2{(f16)a1.x, (f16)a1.y};
        a2[3] = f16x2{(f16)a1.z, (f16)a1.w};
    }

    const int s0 = offsets[t], s1 = offsets[t + 1];
    float acc[8] = {0.f, 0.f, 0.f, 0.f, 0.f, 0.f, 0.f, 0.f};
    float rs = 0.f;

    for (int base = s0; base < s1; base += 64) {
        int cnt = s1 - base;
        if (cnt > 64) cnt = 64;
        int myd = (lane < cnt) ? dsts[base + lane] : 0;
        // pipeline prologue
        int d0 = __shfl(myd, 0, 64);
        uint4 vr = *(const uint4*)(uv + (size_t)(unsigned)d0 * 1024 + voff);
        uint4 hr = *(const uint4*)(h + (size_t)(unsigned)d0 * 512 + hoff);
        for (int j = 0; j < cnt; j++) {
            uint4 vr_n, hr_n;
            if (j + 1 < cnt) {
                int dn = __shfl(myd, j + 1, 64);
                vr_n = *(const uint4*)(uv + (size_t)(unsigned)dn * 1024 + voff);
                hr_n = *(const uint4*)(h + (size_t)(unsigned)dn * 512 + hoff);
            }
            float p = dot8_lrelu(vr, u2, a2);
            p += __shfl_xor(p, 1, 64);
            p += __shfl_xor(p, 2, 64);
            p += __shfl_xor(p, 4, 64);
            float wgt = __expf(p);
            rs += wgt;
            const f16* hp = (const f16*)&hr;
#pragma unroll
            for (int k = 0; k < 8; k++) acc[k] = fmaf(wgt, (float)hp[k], acc[k]);
            vr = vr_n;
            hr = hr_n;
        }
    }
    float inv = 1.f / rs;
    float o[8];
#pragma unroll
    for (int k = 0; k < 8; k++) {
        float hp = acc[k] * inv;
        float e1 = hp > 0.f ? hp : expm1f(hp);
        o[k] = e1 > 0.f ? e1 : expm1f(e1);
    }
    store8h(x2 + (size_t)t * 512 + hoff, o);
}

// ---------------- layer-2 edge/aggregation: one 4B gather per lane per edge ----------------
__global__ void edge_l2(const int* __restrict__ offsets, const int* __restrict__ dsts,
                        const f16x2* __restrict__ vh2, const float* __restrict__ uv2,
                        const float* __restrict__ a_out, float* __restrict__ out, int n) {
    int wave = threadIdx.x >> 6;
    int lane = threadIdx.x & 63;
    int t = blockIdx.x * (blockDim.x >> 6) + wave;
    if (t >= n) return;
    bool act = lane < 40;
    float u_t = act ? uv2[(size_t)t * 80 + lane] : 0.f;
    float a_l = act ? a_out[lane] : 0.f;
    int s0 = offsets[t], s1 = offsets[t + 1];
    float acc = 0.f, rs = 0.f;
    const f16x2 z2 = {(_Float16)0.f, (_Float16)0.f};
    for (int base = s0; base < s1; base += 64) {
        int cnt = s1 - base;
        if (cnt > 64) cnt = 64;
        int myd = (lane < cnt) ? dsts[base + lane] : 0;
        int d0 = __shfl(myd, 0, 64);
        f16x2 vh0 = act ? vh2[(size_t)(unsigned)d0 * 40 + lane] : z2;
        for (int j = 0; j < cnt; j++) {
            f16x2 vh1 = z2;
            if (j + 1 < cnt) {
                int dn = __shfl(myd, j + 1, 64);
                vh1 = act ? vh2[(size_t)(unsigned)dn * 40 + lane] : z2;
            }
            float w = u_t + (float)vh0[0];
            float lr = fmaxf(w, 0.2f * w);
            float p = a_l * lr;
#pragma unroll
            for (int m = 32; m; m >>= 1) p += __shfl_xor(p, m, 64);
            float wgt = __expf(p);
            rs += wgt;
            acc = fmaf(wgt, (float)vh0[1], acc);
            vh0 = vh1;
        }
    }
    if (act) {
        float hp = acc / rs;
        out[(size_t)t * 40 + lane] = hp > 0.f ? hp : expm1f(hp);
    }
}

// ---------------- launch ----------------
extern "C" void kernel_launch(void* const* d_in, const int* in_sizes, int n_in,
                              void* d_out, int out_size, void* d_ws, size_t ws_size,
                              hipStream_t stream) {
    const float* x         = (const float*)d_in[0];
    const int*   edge      = (const int*)d_in[1];
    const float* W         = (const float*)d_in[2];
    const float* W_pair    = (const float*)d_in[3];
    const float* a         = (const float*)d_in[4];
    const float* W_out     = (const float*)d_in[5];
    const float* W_pair_out= (const float*)d_in[6];
    const float* a_out     = (const float*)d_in[7];
    float* out = (float*)d_out;

    const int n  = in_sizes[0] / FEAT;   // 50000
    const int ne = in_sizes[1] / 2;      // 1,650,000
    const int* srcArr = edge;
    const int* dstArr = edge + ne;

    char* ws = (char*)d_ws;
    size_t off = 0;
    auto alloc = [&](size_t bytes) -> void* {
        void* p = ws + off;
        off = (off + bytes + 255) & ~(size_t)255;
        return p;
    };
    f16* h    = (f16*)alloc((size_t)n * 512 * sizeof(f16));      // [N][512]; later aliased by h2/uv2
    f16* uv   = (f16*)alloc((size_t)n * 1024 * sizeof(f16));     // [N][1024]
    f16* x2   = (f16*)alloc((size_t)n * 512 * sizeof(f16));      // [N][512]
    f16x2* vh2 = (f16x2*)alloc((size_t)n * 40 * sizeof(f16x2));  // [N][40] {v2,h2}
    f16* Wh_t = (f16*)alloc(512 * 512 * sizeof(f16));
    f16* Bp_t = (f16*)alloc(8 * 128 * 64 * sizeof(f16));
    f16* Wo_t = (f16*)alloc(40 * 512 * sizeof(f16));
    float* B2p = (float*)alloc(40 * 80 * sizeof(float));
    int* counts  = (int*)alloc((size_t)n * sizeof(int));
    int* offsets = (int*)alloc((size_t)(n + 1) * sizeof(int));
    int* cursor  = (int*)alloc((size_t)n * sizeof(int));
    int* partial = (int*)alloc(1024 * sizeof(int));
    int* dsts    = (int*)alloc((size_t)ne * sizeof(int));
    float* h2  = (float*)h;                          // h dead after edge_l1
    float* uv2 = (float*)((char*)h + (size_t)n * 40 * sizeof(float));

    const int nb = (n + 255) / 256;   // 196 scan blocks

    // CSR build (+ per-segment source sort for gather locality)
    hipMemsetAsync(counts, 0, (size_t)n * sizeof(int), stream);
    hist_kernel<<<2048, 256, 0, stream>>>(srcArr, counts, ne);
    scan_partial<<<nb, 256, 0, stream>>>(counts, partial, n);
    scan_top<<<1, 1024, 0, stream>>>(partial, nb);
    scan_final<<<nb, 256, 0, stream>>>(counts, partial, offsets, cursor, n);
    scatter_kernel<<<2048, 256, 0, stream>>>(srcArr, dstArr, cursor, dsts, ne);
    sort_dsts<<<(n + 3) / 4, 256, 0, stream>>>(offsets, dsts, n);

    // weight packs
    pack_Wh<<<(512 * 512 + 255) / 256, 256, 0, stream>>>(W, Wh_t);
    pack_Bp<<<(8 * 128 * 64 + 255) / 256, 256, 0, stream>>>(W_pair, Bp_t);
    pack_Wo<<<(40 * 512 + 255) / 256, 256, 0, stream>>>(W_out, Wo_t);
    repack_wpo<<<(40 * 80 + 255) / 256, 256, 0, stream>>>(W_pair_out, B2p);

    const int mBlocks = (n + 127) / 128;   // 391

    // h = f16(x) @ Wh   [N,512] f16  (f32->f16 conversion fused into A staging)
    gemm_mfma<float, f16><<<dim3(mBlocks, 1, 4), 256, 0, stream>>>(
        x, 512, 0, 0, Wh_t, 0, 512, h, 512, 0, n, 512);

    // uv[:, head*128+c] = h[:, head*64 + k] @ Bp_t[head]   (K=64, per-head batch)
    gemm_mfma<f16, f16><<<dim3(mBlocks, 8, 1), 256, 0, stream>>>(
        h, 512, 0, 64, Bp_t, 128L * 64, 64, uv, 1024, 128, n, 128);

    // layer-1 edge phase -> x2
    edge_l1<<<dim3((n + 3) / 4), 256, 0, stream>>>(offsets, dsts, h, uv, a, x2, n);

    // h2 = x2 @ W_out  [N,40] f32 (aliases h)
    gemm_mfma<f16, float><<<dim3(mBlocks, 1, 1), 256, 0, stream>>>(
        x2, 512, 0, 0, Wo_t, 0, 512, h2, 40, 0, n, 40);

    // uv2 = h2 @ B2p  [N,80] f32
    gemm_kernel<<<dim3((n + 63) / 64, 1, 2), 256, 0, stream>>>(
        h2, 40, B2p, 80, uv2, 80, n, 40, 80);

    // pack interleaved {v2,h2} f16 pairs for single-gather edge_l2
    pack_vh2<<<(n * 40 + 255) / 256, 256, 0, stream>>>(h2, uv2, vh2, n * 40);

    // layer-2 edge phase -> out
    edge_l2<<<dim3((n + 3) / 4), 256, 0, stream>>>(offsets, dsts, vh2, uv2, a_out, out, n);
}

// Round 7
// 925.919 us; speedup vs baseline: 1.2363x; 1.1480x over previous
//
#include <hip/hip_runtime.h>
#include <hip/hip_bf16.h>
#include <hip/hip_fp16.h>

typedef _Float16 f16;
typedef _Float16 f16x2 __attribute__((ext_vector_type(2)));
typedef _Float16 f16x8 __attribute__((ext_vector_type(8)));
typedef float f32x4 __attribute__((ext_vector_type(4)));

#define HEADS 8
#define HID 64
#define NCLS 40
#define FEAT 512

// ---------------- merged weight packing ----------------
// Wh_t[c][k] = W[c>>6][k][c&63]            (262144 f16)
// Bp_t[head][c][k] = Wp[head][(c>>6)*64+k][c&63]  (65536 f16)
// Wo_t[c][k] = Wo[k][c]                    (20480 f16)
// B2p[k][p*40+j] = Wpo[(p*40+k)*40+j]      (3200 f32)
__global__ void pack_all(const float* __restrict__ W, const float* __restrict__ Wp,
                         const float* __restrict__ Wo, const float* __restrict__ Wpo,
                         f16* __restrict__ Wh_t, f16* __restrict__ Bp_t,
                         f16* __restrict__ Wo_t, float* __restrict__ B2p) {
    int idx = blockIdx.x * blockDim.x + threadIdx.x;
    if (idx < 512 * 512) {
        int c = idx >> 9, k = idx & 511;
        Wh_t[idx] = (f16)W[(c >> 6) * 512 * 64 + k * 64 + (c & 63)];
    } else if (idx < 512 * 512 + 8 * 128 * 64) {
        int i = idx - 512 * 512;
        int head = i >> 13, c = (i >> 6) & 127, k = i & 63;
        Bp_t[i] = (f16)Wp[head * 8192 + ((c >> 6) * 64 + k) * 64 + (c & 63)];
    } else if (idx < 512 * 512 + 8 * 128 * 64 + 40 * 512) {
        int i = idx - (512 * 512 + 8 * 128 * 64);
        int c = i >> 9, k = i & 511;
        Wo_t[i] = (f16)Wo[k * 40 + c];
    } else if (idx < 512 * 512 + 8 * 128 * 64 + 40 * 512 + 40 * 80) {
        int i = idx - (512 * 512 + 8 * 128 * 64 + 40 * 512);
        int k = i / 80, c = i % 80;
        int p = c / 40, j = c % 40;
        B2p[i] = Wpo[(p * 40 + k) * 40 + j];
    }
}

// vh2[t][k] = {f16(v2[t][k]), f16(h2[t][k])}  — one 4B gather per lane in edge_l2
__global__ void pack_vh2(const float* __restrict__ h2, const float* __restrict__ uv2,
                         f16x2* __restrict__ vh2, int total) {
    int i = blockIdx.x * blockDim.x + threadIdx.x;
    if (i >= total) return;
    int t = i / 40, k = i % 40;
    vh2[i] = f16x2{(f16)uv2[(size_t)t * 80 + 40 + k], (f16)h2[i]};
}

// ---------------- CSR build (group edges by src == target row) ----------------
__global__ void hist_kernel(const int* __restrict__ src, int* __restrict__ counts, int ne) {
    int i = blockIdx.x * blockDim.x + threadIdx.x;
    int stride = gridDim.x * blockDim.x;
    for (; i < ne; i += stride) atomicAdd(&counts[src[i]], 1);
}

// hierarchical exclusive scan: partial sums (196 blocks) -> top scan (1 block) -> final
__global__ void scan_partial(const int* __restrict__ counts, int* __restrict__ partial, int n) {
    __shared__ int s[256];
    int i = blockIdx.x * 256 + threadIdx.x;
    s[threadIdx.x] = (i < n) ? counts[i] : 0;
    __syncthreads();
    for (int d = 128; d > 0; d >>= 1) {
        if (threadIdx.x < d) s[threadIdx.x] += s[threadIdx.x + d];
        __syncthreads();
    }
    if (threadIdx.x == 0) partial[blockIdx.x] = s[0];
}

__global__ void scan_top(int* __restrict__ partial, int nb) {
    __shared__ int s[1024];
    int tid = threadIdx.x;
    s[tid] = (tid < nb) ? partial[tid] : 0;
    __syncthreads();
    for (int d = 1; d < 1024; d <<= 1) {
        int v = (tid >= d) ? s[tid - d] : 0;
        __syncthreads();
        s[tid] += v;
        __syncthreads();
    }
    if (tid < nb) partial[tid] = (tid == 0) ? 0 : s[tid - 1];  // exclusive
}

__global__ void scan_final(const int* __restrict__ counts, const int* __restrict__ partialEx,
                           int* __restrict__ offsets, int* __restrict__ cursor, int n) {
    __shared__ int s[256];
    int i = blockIdx.x * 256 + threadIdx.x;
    int v = (i < n) ? counts[i] : 0;
    s[threadIdx.x] = v;
    __syncthreads();
    for (int d = 1; d < 256; d <<= 1) {
        int u = (threadIdx.x >= d) ? s[threadIdx.x - d] : 0;
        __syncthreads();
        s[threadIdx.x] += u;
        __syncthreads();
    }
    int excl = partialEx[blockIdx.x] + s[threadIdx.x] - v;
    if (i < n) {
        cursor[i] = excl;
        offsets[i] = excl;
        if (i == n - 1) offsets[n] = excl + v;
    }
}

__global__ void scatter_kernel(const int* __restrict__ src, const int* __restrict__ dst,
                               int* __restrict__ cursor, int* __restrict__ dsts, int ne) {
    int i = blockIdx.x * blockDim.x + threadIdx.x;
    int stride = gridDim.x * blockDim.x;
    for (; i < ne; i += stride) {
        int pos = atomicAdd(&cursor[src[i]], 1);
        dsts[pos] = dst[i];
    }
}

// ---------------- MFMA f16 GEMM: 128x128 tile, BK=32, 4 waves ----------------
__device__ __forceinline__ void stC(float* p, float v) { *p = v; }
__device__ __forceinline__ void stC(f16* p, float v) { *p = (f16)v; }
__device__ __forceinline__ f16x8 ldA8(const f16* p) { return *(const f16x8*)p; }
__device__ __forceinline__ f16x8 ldA8(const float* p) {
    float4 a = ((const float4*)p)[0];
    float4 b = ((const float4*)p)[1];
    f16x8 r = {(f16)a.x, (f16)a.y, (f16)a.z, (f16)a.w, (f16)b.x, (f16)b.y, (f16)b.z, (f16)b.w};
    return r;
}

// A [M][lda] (cols a0.. a0+K), Bt [batch][ncols][K] f16 (transposed), C [M][ldc]
template <typename AT, typename CT>
__global__ __launch_bounds__(256)
void gemm_mfma(const AT* __restrict__ A, int lda, int acol0, int acolStride,
               const f16* __restrict__ Bt, long bBatchStride, int K,
               CT* __restrict__ C, int ldc, int ccolStride,
               int nrows, int ncols) {
    __shared__ f16 As[128][40];   // BK=32 padded to 40 (80B rows -> 2-way max on b128 reads)
    __shared__ f16 Bs[128][40];
    const int batch = blockIdx.y;
    const int row0 = blockIdx.x * 128;
    const int col0 = blockIdx.z * 128;
    const int a0 = acol0 + batch * acolStride;
    const f16* Bb = Bt + (size_t)batch * bBatchStride;
    const int tid = threadIdx.x;
    const int lane = tid & 63;
    const int wave = tid >> 6;
    const int wr = (wave >> 1) * 64;
    const int wc = (wave & 1) * 64;
    f32x4 acc[4][4] = {};

    for (int k0 = 0; k0 < K; k0 += 32) {
#pragma unroll
        for (int i = 0; i < 2; i++) {
            int idx = tid + i * 256;
            int r = idx >> 2, ch = idx & 3;
            int gr = row0 + r;
            f16x8 val = {};
            if (gr < nrows) val = ldA8(A + (size_t)gr * lda + a0 + k0 + ch * 8);
            *(f16x8*)(&As[r][ch * 8]) = val;
        }
#pragma unroll
        for (int i = 0; i < 2; i++) {
            int idx = tid + i * 256;
            int r = idx >> 2, ch = idx & 3;
            int gc = col0 + r;
            f16x8 val = {};
            if (gc < ncols) val = *(const f16x8*)(Bb + (size_t)gc * K + k0 + ch * 8);
            *(f16x8*)(&Bs[r][ch * 8]) = val;
        }
        __syncthreads();
        f16x8 af[4], bf[4];
#pragma unroll
        for (int t = 0; t < 4; t++)
            af[t] = *(const f16x8*)(&As[wr + t * 16 + (lane & 15)][(lane >> 4) * 8]);
#pragma unroll
        for (int t = 0; t < 4; t++)
            bf[t] = *(const f16x8*)(&Bs[wc + t * 16 + (lane & 15)][(lane >> 4) * 8]);
#pragma unroll
        for (int i = 0; i < 4; i++)
#pragma unroll
            for (int j = 0; j < 4; j++)
                acc[i][j] = __builtin_amdgcn_mfma_f32_16x16x32_f16(af[i], bf[j], acc[i][j], 0, 0, 0);
        __syncthreads();
    }
    // C/D layout: col = lane&15, row = (lane>>4)*4 + r   [HW-verified]
    const int crow = (lane >> 4) * 4;
    const int ccol = lane & 15;
#pragma unroll
    for (int i = 0; i < 4; i++) {
#pragma unroll
        for (int j = 0; j < 4; j++) {
            int gc = col0 + wc + j * 16 + ccol;
            if (gc >= ncols) continue;
#pragma unroll
            for (int r = 0; r < 4; r++) {
                int gr = row0 + wr + i * 16 + crow + r;
                if (gr < nrows)
                    stC(&C[(size_t)gr * ldc + (size_t)batch * ccolStride + gc], acc[i][j][r]);
            }
        }
    }
}

// ---------------- tiny fp32 vector GEMM (kept for uv2: K=40, N=80) ----------------
__global__ void gemm_kernel(const float* __restrict__ A, int lda,
                            const float* __restrict__ B, int ldb,
                            float* __restrict__ C, int ldc,
                            int nrows, int K, int ncols) {
    __shared__ __align__(16) float As[16][68];
    __shared__ __align__(16) float Bs[16][64];
    const int colblk = blockIdx.z * 64;
    const int row0 = blockIdx.x * 64;
    const int tid = threadIdx.x;
    const int tm = tid >> 4, tn = tid & 15;
    float acc[4][4] = {};
    for (int k0 = 0; k0 < K; k0 += 16) {
#pragma unroll
        for (int i = 0; i < 4; i++) {
            int idx = tid + i * 256;
            int m = idx >> 4;
            int k = idx & 15;
            int gr = row0 + m;
            float v = 0.f;
            if (gr < nrows && (k0 + k) < K) v = A[(size_t)gr * lda + k0 + k];
            As[k][m] = v;
        }
#pragma unroll
        for (int i = 0; i < 4; i++) {
            int idx = tid + i * 256;
            int k = idx >> 6;
            int j = idx & 63;
            float v = 0.f;
            if ((k0 + k) < K && (colblk + j) < ncols) v = B[(size_t)(k0 + k) * ldb + colblk + j];
            Bs[k][j] = v;
        }
        __syncthreads();
#pragma unroll
        for (int k = 0; k < 16; k++) {
            float av[4], bv[4];
#pragma unroll
            for (int i = 0; i < 4; i++) av[i] = As[k][tm * 4 + i];
#pragma unroll
            for (int j = 0; j < 4; j++) bv[j] = Bs[k][tn * 4 + j];
#pragma unroll
            for (int i = 0; i < 4; i++)
#pragma unroll
                for (int j = 0; j < 4; j++) acc[i][j] += av[i] * bv[j];
        }
        __syncthreads();
    }
#pragma unroll
    for (int i = 0; i < 4; i++) {
        int gr = row0 + tm * 4 + i;
        if (gr >= nrows) continue;
#pragma unroll
        for (int j = 0; j < 4; j++) {
            int gc = colblk + tn * 4 + j;
            if (gc < ncols) C[(size_t)gr * ldc + gc] = acc[i][j];
        }
    }
}

// ---------------- helpers ----------------
__device__ __forceinline__ void store8h(f16* p, const float o[8]) {
    f16x8 v;
#pragma unroll
    for (int k = 0; k < 8; k++) v[k] = (f16)o[k];
    *(f16x8*)p = v;
}

__device__ __forceinline__ float dot8_lrelu(const uint4& vr, const f16x2 u2[4],
                                            const f16x2 a2[4]) {
    const f16x2* vp = (const f16x2*)&vr;
    float p = 0.f;
#pragma unroll
    for (int k = 0; k < 4; k++) {
        f16x2 w = u2[k] + vp[k];
        f16x2 lr = __builtin_elementwise_max(w, w * (_Float16)0.2f);
#if __has_builtin(__builtin_amdgcn_fdot2)
        p = __builtin_amdgcn_fdot2(lr, a2[k], p, false);
#else
        p = fmaf((float)lr[0], (float)a2[k][0], p);
        p = fmaf((float)lr[1], (float)a2[k][1], p);
#endif
    }
    return p;
}

// ---------------- layer-1 edge/aggregation: one wave per target, ALL 8 heads ----------------
// lane l serves head l>>3, dims (l&7)*8 .. +7; 2-deep software-pipelined gather.
__global__ void edge_l1(const int* __restrict__ offsets, const int* __restrict__ dsts,
                        const f16* __restrict__ h, const f16* __restrict__ uv,
                        const float* __restrict__ a, f16* __restrict__ x2, int n) {
    const int lane = threadIdx.x & 63;
    const int wave = threadIdx.x >> 6;
    const int t = blockIdx.x * (blockDim.x >> 6) + wave;
    if (t >= n) return;
    const int head = lane >> 3;
    const int sub = lane & 7;
    const unsigned voff = head * 128 + 64 + sub * 8;
    const unsigned uoff = head * 128 + sub * 8;
    const unsigned hoff = lane * 8;

    f16x2 u2[4], a2[4];
    {
        uint4 ur = *(const uint4*)(uv + (size_t)t * 1024 + uoff);
        const f16x2* up = (const f16x2*)&ur;
#pragma unroll
        for (int k = 0; k < 4; k++) u2[k] = up[k];
        const float4* ap = (const float4*)(a + hoff);
        float4 a0 = ap[0], a1 = ap[1];
        a2[0] = f16x2{(f16)a0.x, (f16)a0.y};
        a2[1] = f16x2{(f16)a0.z, (f16)a0.w};
        a2[2] = f16x2{(f16)a1.x, (f16)a1.y};
        a2[3] = f16x2{(f16)a1.z, (f16)a1.w};
    }

    const int s0 = offsets[t], s1 = offsets[t + 1];
    float acc[8] = {0.f, 0.f, 0.f, 0.f, 0.f, 0.f, 0.f, 0.f};
    float rs = 0.f;

    for (int base = s0; base < s1; base += 64) {
        int cnt = s1 - base;
        if (cnt > 64) cnt = 64;
        int myd = (lane < cnt) ? dsts[base + lane] : 0;
        // pipeline prologue
        int d0 = __shfl(myd, 0, 64);
        uint4 vr = *(const uint4*)(uv + (size_t)(unsigned)d0 * 1024 + voff);
        uint4 hr = *(const uint4*)(h + (size_t)(unsigned)d0 * 512 + hoff);
        for (int j = 0; j < cnt; j++) {
            uint4 vr_n, hr_n;
            if (j + 1 < cnt) {
                int dn = __shfl(myd, j + 1, 64);
                vr_n = *(const uint4*)(uv + (size_t)(unsigned)dn * 1024 + voff);
                hr_n = *(const uint4*)(h + (size_t)(unsigned)dn * 512 + hoff);
            }
            float p = dot8_lrelu(vr, u2, a2);
            p += __shfl_xor(p, 1, 64);
            p += __shfl_xor(p, 2, 64);
            p += __shfl_xor(p, 4, 64);
            float wgt = __expf(p);
            rs += wgt;
            const f16* hp = (const f16*)&hr;
#pragma unroll
            for (int k = 0; k < 8; k++) acc[k] = fmaf(wgt, (float)hp[k], acc[k]);
            vr = vr_n;
            hr = hr_n;
        }
    }
    float inv = 1.f / rs;
    float o[8];
#pragma unroll
    for (int k = 0; k < 8; k++) {
        float hp = acc[k] * inv;
        float e1 = hp > 0.f ? hp : expm1f(hp);
        o[k] = e1 > 0.f ? e1 : expm1f(e1);
    }
    store8h(x2 + (size_t)t * 512 + hoff, o);
}

// ---------------- layer-2 edge/aggregation: 8 edges in flight per wave ----------------
// lane = (edge-slot g = lane>>3, dim-slice s = lane&7, dims s*5..s*5+4).
// vh2[d][k] = {v2,h2} f16 pairs (L2-resident, 4 MB); u2 from uv2 f32 per target.
__global__ void edge_l2(const int* __restrict__ offsets, const int* __restrict__ dsts,
                        const f16x2* __restrict__ vh2, const float* __restrict__ uv2,
                        const float* __restrict__ a_out, float* __restrict__ out, int n) {
    const int lane = threadIdx.x & 63;
    const int wave = threadIdx.x >> 6;
    const int t = blockIdx.x * (blockDim.x >> 6) + wave;
    if (t >= n) return;
    const int g = lane >> 3;       // edge slot 0..7
    const int s = lane & 7;        // dim slice: dims s*5 .. s*5+4
    float u5[5], a5[5];
#pragma unroll
    for (int k = 0; k < 5; k++) {
        u5[k] = uv2[(size_t)t * 80 + s * 5 + k];
        a5[k] = a_out[s * 5 + k];
    }
    const int s0 = offsets[t], s1 = offsets[t + 1];
    float acc[5] = {0.f, 0.f, 0.f, 0.f, 0.f};
    float rs = 0.f;
    for (int base = s0; base < s1; base += 64) {
        int cnt = s1 - base;
        if (cnt > 64) cnt = 64;
        int myd = (lane < cnt) ? dsts[base + lane] : 0;
        for (int j8 = 0; j8 < cnt; j8 += 8) {
            int eidx = j8 + g;
            bool active = eidx < cnt;
            int d = __shfl(myd, active ? eidx : 0, 64);
            f16x2 vh[5];
            const f16x2* vp = vh2 + (size_t)(unsigned)d * 40 + s * 5;
#pragma unroll
            for (int k = 0; k < 5; k++) vh[k] = vp[k];
            float p = 0.f;
#pragma unroll
            for (int k = 0; k < 5; k++) {
                float w = u5[k] + (float)vh[k][0];
                p = fmaf(a5[k], fmaxf(w, 0.2f * w), p);
            }
            p += __shfl_xor(p, 1, 64);
            p += __shfl_xor(p, 2, 64);
            p += __shfl_xor(p, 4, 64);
            float wgt = active ? __expf(p) : 0.f;
            rs += wgt;
#pragma unroll
            for (int k = 0; k < 5; k++) acc[k] = fmaf(wgt, (float)vh[k][1], acc[k]);
        }
    }
    rs += __shfl_xor(rs, 8, 64);
    rs += __shfl_xor(rs, 16, 64);
    rs += __shfl_xor(rs, 32, 64);
#pragma unroll
    for (int k = 0; k < 5; k++) {
        acc[k] += __shfl_xor(acc[k], 8, 64);
        acc[k] += __shfl_xor(acc[k], 16, 64);
        acc[k] += __shfl_xor(acc[k], 32, 64);
    }
    if (g == 0) {
        float inv = 1.f / rs;
#pragma unroll
        for (int k = 0; k < 5; k++) {
            float hp = acc[k] * inv;
            out[(size_t)t * 40 + s * 5 + k] = hp > 0.f ? hp : expm1f(hp);
        }
    }
}

// ---------------- launch ----------------
extern "C" void kernel_launch(void* const* d_in, const int* in_sizes, int n_in,
                              void* d_out, int out_size, void* d_ws, size_t ws_size,
                              hipStream_t stream) {
    const float* x         = (const float*)d_in[0];
    const int*   edge      = (const int*)d_in[1];
    const float* W         = (const float*)d_in[2];
    const float* W_pair    = (const float*)d_in[3];
    const float* a         = (const float*)d_in[4];
    const float* W_out     = (const float*)d_in[5];
    const float* W_pair_out= (const float*)d_in[6];
    const float* a_out     = (const float*)d_in[7];
    float* out = (float*)d_out;

    const int n  = in_sizes[0] / FEAT;   // 50000
    const int ne = in_sizes[1] / 2;      // 1,650,000
    const int* srcArr = edge;
    const int* dstArr = edge + ne;

    char* ws = (char*)d_ws;
    size_t off = 0;
    auto alloc = [&](size_t bytes) -> void* {
        void* p = ws + off;
        off = (off + bytes + 255) & ~(size_t)255;
        return p;
    };
    f16* h    = (f16*)alloc((size_t)n * 512 * sizeof(f16));      // [N][512]; later aliased by h2/uv2
    f16* uv   = (f16*)alloc((size_t)n * 1024 * sizeof(f16));     // [N][1024]
    f16* x2   = (f16*)alloc((size_t)n * 512 * sizeof(f16));      // [N][512]
    f16x2* vh2 = (f16x2*)alloc((size_t)n * 40 * sizeof(f16x2));  // [N][40] {v2,h2}
    f16* Wh_t = (f16*)alloc(512 * 512 * sizeof(f16));
    f16* Bp_t = (f16*)alloc(8 * 128 * 64 * sizeof(f16));
    f16* Wo_t = (f16*)alloc(40 * 512 * sizeof(f16));
    float* B2p = (float*)alloc(40 * 80 * sizeof(float));
    int* counts  = (int*)alloc((size_t)n * sizeof(int));
    int* offsets = (int*)alloc((size_t)(n + 1) * sizeof(int));
    int* cursor  = (int*)alloc((size_t)n * sizeof(int));
    int* partial = (int*)alloc(1024 * sizeof(int));
    int* dsts    = (int*)alloc((size_t)ne * sizeof(int));
    float* h2  = (float*)h;                          // h dead after edge_l1
    float* uv2 = (float*)((char*)h + (size_t)n * 40 * sizeof(float));

    const int nb = (n + 255) / 256;   // 196 scan blocks

    // CSR build
    hipMemsetAsync(counts, 0, (size_t)n * sizeof(int), stream);
    hist_kernel<<<2048, 256, 0, stream>>>(srcArr, counts, ne);
    scan_partial<<<nb, 256, 0, stream>>>(counts, partial, n);
    scan_top<<<1, 1024, 0, stream>>>(partial, nb);
    scan_final<<<nb, 256, 0, stream>>>(counts, partial, offsets, cursor, n);
    scatter_kernel<<<2048, 256, 0, stream>>>(srcArr, dstArr, cursor, dsts, ne);

    // weight packs (single launch)
    const int packTotal = 512 * 512 + 8 * 128 * 64 + 40 * 512 + 40 * 80;
    pack_all<<<(packTotal + 255) / 256, 256, 0, stream>>>(
        W, W_pair, W_out, W_pair_out, Wh_t, Bp_t, Wo_t, B2p);

    const int mBlocks = (n + 127) / 128;   // 391

    // h = f16(x) @ Wh   [N,512] f16  (f32->f16 conversion fused into A staging)
    gemm_mfma<float, f16><<<dim3(mBlocks, 1, 4), 256, 0, stream>>>(
        x, 512, 0, 0, Wh_t, 0, 512, h, 512, 0, n, 512);

    // uv[:, head*128+c] = h[:, head*64 + k] @ Bp_t[head]   (K=64, per-head batch)
    gemm_mfma<f16, f16><<<dim3(mBlocks, 8, 1), 256, 0, stream>>>(
        h, 512, 0, 64, Bp_t, 128L * 64, 64, uv, 1024, 128, n, 128);

    // layer-1 edge phase -> x2
    edge_l1<<<dim3((n + 3) / 4), 256, 0, stream>>>(offsets, dsts, h, uv, a, x2, n);

    // h2 = x2 @ W_out  [N,40] f32 (aliases h)
    gemm_mfma<f16, float><<<dim3(mBlocks, 1, 1), 256, 0, stream>>>(
        x2, 512, 0, 0, Wo_t, 0, 512, h2, 40, 0, n, 40);

    // uv2 = h2 @ B2p  [N,80] f32
    gemm_kernel<<<dim3((n + 63) / 64, 1, 2), 256, 0, stream>>>(
        h2, 40, B2p, 80, uv2, 80, n, 40, 80);

    // pack interleaved {v2,h2} f16 pairs for single-gather edge_l2
    pack_vh2<<<(n * 40 + 255) / 256, 256, 0, stream>>>(h2, uv2, vh2, n * 40);

    // layer-2 edge phase -> out
    edge_l2<<<dim3((n + 3) / 4), 256, 0, stream>>>(offsets, dsts, vh2, uv2, a_out, out, n);
}